// Round 17
// baseline (1110.724 us; speedup 1.0000x reference)
//
#include <hip/hip_runtime.h>

// ============================================================================
// RetinaNetHead (S2ANet-style rotated head), MI355X gfx950.
// R17: deep counted pipeline + R16 interleave. R16 (45% MfmaUtil) is
//   LDS-throughput-bound (per-CU model: 2950 LDS cyc vs 1242 MFMA cyc per
//   K-step; ceiling ~68%); remaining stalls = vmcnt(0) end-of-step drain.
//   Now: BK=32, FOUR buffers (A 4x16K + B 4x16K = 128KB, stride buf<<13 --
//   R14's buf<<12 overlapped!), stage(t+3) issued at step t, vmcnt(8) at step
//   end (8/4/0 tail), ONE bare barrier/step, counted-lgkm read||MFMA bursts.
//   conv1's two towers merged into one dispatch (grid.y selects tower).
// fp32 accum; logits/decode fp32.
//
// Sync: end of step u waits vmcnt(8)=stage(u+1) done (loads retire in order;
// 8 = stages u+2,u+3). Barrier at top of u+1 makes it block-visible. WAR:
// stage at u writes buf (u+3)&3 == (u-1)&3, whose reads retired before the
// barrier at top of u (lgkm(0) in step u-1). Tail: vm 4 @69, 0 @70/71.
//
// Level geometry: rows gm 0..174591; cum={0,131072,163840,172032,174080,174592}
// Workspace (ushort units), same footprint (~245.1MB):
//   [0) feats NHWC fp16 (reused as t2) | [44,695,552) t1r | [78,249,984) t1c
//   [111,804,416) conv w 4x[9][256][256] | [114,163,712) wh | [114,171,904) wc
//   [114,188,288) zp | byte 228,376,704: hbuf fp32 [174592][24]
// ============================================================================

typedef __attribute__((ext_vector_type(8))) _Float16 f16x8;
typedef __attribute__((ext_vector_type(4))) float f32x4;

#define SCORES_TOTAL 10475520ull  // 8*87296*15

__device__ __forceinline__ unsigned short f2h(float f) {
  union { _Float16 h; unsigned short u; } x;
  x.h = (_Float16)f;
  return x.u;
}

__device__ __forceinline__ float sigmf(float x) {
  return 1.0f / (1.0f + expf(-x));
}

__device__ __forceinline__ void gload_lds16(const unsigned short* g,
                                            unsigned short* l) {
  __builtin_amdgcn_global_load_lds(
      (const __attribute__((address_space(1))) unsigned int*)g,
      (__attribute__((address_space(3))) unsigned int*)l, 16, 0, 0);
}

__device__ __forceinline__ unsigned lds_addr(const void* p) {
  return (unsigned)(size_t)(const __attribute__((address_space(3))) char*)p;
}

// clobber-free ds_read_b128 with literal byte offset (volatile keeps order)
#define DSR(d, va, off) \
  asm volatile("ds_read_b128 %0, %1 offset:" off : "=v"(d) : "v"(va))

__device__ __forceinline__ void lvl_lookup(int gm, int& logW, int& mbase) {
  if (gm < 131072) { logW = 7; mbase = 0; }
  else if (gm < 163840) { logW = 6; mbase = 131072; }
  else if (gm < 172032) { logW = 5; mbase = 163840; }
  else if (gm < 174080) { logW = 4; mbase = 172032; }
  else { logW = 3; mbase = 174080; }
}

// ---------------------------------------------------------------- weight prep
__global__ __launch_bounds__(256) void prep_convw(
    const float* __restrict__ w0, const float* __restrict__ w1,
    const float* __restrict__ w2, const float* __restrict__ w3,
    unsigned short* __restrict__ wtout) {
  int g = blockIdx.x * 256 + threadIdx.x;  // < 4*589824
  int q = g >> 16;
  int wsel = q / 9;
  int kk = q - wsel * 9;
  int r = g & 65535;
  int oc = r >> 8, ic = r & 255;
  const float* src = (wsel == 0) ? w0 : (wsel == 1) ? w1 : (wsel == 2) ? w2 : w3;
  float v = src[(size_t)(oc * 256 + ic) * 9 + kk];
  wtout[(size_t)wsel * 589824 + (size_t)((kk << 8) + oc) * 256 + ic] = f2h(v);
}

__global__ __launch_bounds__(256) void prep_small(
    const float* __restrict__ clsh, const float* __restrict__ regh,
    const float* __restrict__ confw,
    unsigned short* __restrict__ wc, unsigned short* __restrict__ wh,
    unsigned short* __restrict__ zp) {
  int g = blockIdx.x * 256 + threadIdx.x;
  if (g < 16384) {
    int row = g >> 8, ic = g & 255;
    float v = (row < 60) ? clsh[row * 256 + ic] : 0.0f;
    wc[g] = f2h(v);
  } else if (g < 24576) {
    int gg = g - 16384;
    int row = gg >> 8, ic = gg & 255;
    float v = 0.0f;
    if (row < 20) v = regh[row * 256 + ic];
    else if (row < 24) v = confw[(row - 20) * 256 + ic];
    wh[gg] = f2h(v);
  } else if (g < 24640) {
    zp[g - 24576] = 0;
  }
}

// ------------------------------- NCHW fp32 -> NHWC fp16, all levels merged
__global__ __launch_bounds__(256) void to_nhwc_all(
    const float* __restrict__ f0, const float* __restrict__ f1,
    const float* __restrict__ f2, const float* __restrict__ f3,
    const float* __restrict__ f4, unsigned short* __restrict__ out) {
  __shared__ unsigned short L[64][258];
  const int t = threadIdx.x;
  const int gm0 = blockIdx.x * 64;
  int logW, mbase;
  const float* in;
  if (gm0 < 131072) { logW = 7; mbase = 0; in = f0; }
  else if (gm0 < 163840) { logW = 6; mbase = 131072; in = f1; }
  else if (gm0 < 172032) { logW = 5; mbase = 163840; in = f2; }
  else if (gm0 < 174080) { logW = 4; mbase = 172032; in = f3; }
  else { logW = 3; mbase = 174080; in = f4; }
  const int logHW = 2 * logW;
  const int HW = 1 << logHW;
  const int lm0 = gm0 - mbase;
  const int b = lm0 >> logHW;
  const int hw0 = lm0 & (HW - 1);
#pragma unroll
  for (int it = 0; it < 16; ++it) {
    int c = it * 16 + (t >> 4);
    int j4 = (t & 15) * 4;
    float4 v = *reinterpret_cast<const float4*>(
        in + (size_t)(b * 256 + c) * HW + hw0 + j4);
    L[j4 + 0][c] = f2h(v.x);
    L[j4 + 1][c] = f2h(v.y);
    L[j4 + 2][c] = f2h(v.z);
    L[j4 + 3][c] = f2h(v.w);
  }
  __syncthreads();
#pragma unroll
  for (int it = 0; it < 16; ++it) {
    int j = it * 4 + (t >> 6);
    int c4 = (t & 63) * 4;
    unsigned v0 = (unsigned)L[j][c4 + 0] | ((unsigned)L[j][c4 + 1] << 16);
    unsigned v1 = (unsigned)L[j][c4 + 2] | ((unsigned)L[j][c4 + 3] << 16);
    uint2 v = make_uint2(v0, v1);
    *reinterpret_cast<uint2*>(out + ((size_t)(gm0 + j) << 8) + c4) = v;
  }
}

// ---- conv3x3: 256Mx256N, BK=32, 72 steps, 4-buffer counted pipeline.
// grid.y selects tower (wtA/biasA/outA vs wtB/...); conv2 passes same twice.
__global__ __launch_bounds__(512, 2) void conv256q(
    const unsigned short* __restrict__ xin,   // virtual base: rows at abs gm
    const unsigned short* __restrict__ wtA,
    const unsigned short* __restrict__ wtB,
    const float* __restrict__ biasA, const float* __restrict__ biasB,
    const unsigned short* __restrict__ zp,
    unsigned short* __restrict__ outA, unsigned short* __restrict__ outB,
    int gm_base) {
  __shared__ unsigned short pool[65536];  // A 4x8192 | B 4x8192 (elems)
  const int sel = blockIdx.y;
  const unsigned short* wt = sel ? wtB : wtA;
  const float* bias = sel ? biasB : biasA;
  unsigned short* yout = sel ? outB : outA;

  const int t = threadIdx.x;
  const int lane = t & 63;
  const int wv = t >> 6;       // 0..7
  const int wm = wv >> 2;      // 0..1
  const int wn = wv & 3;       // 0..3
  const int gm0 = gm_base + blockIdx.x * 256;
  int logW, mbase;
  lvl_lookup(gm0, logW, mbase);
  const int H = 1 << logW, W = H;
  const int logHW = 2 * logW;
  const int HWm1 = (1 << logHW) - 1, Wm1 = W - 1;

  // staging: 2 A + 2 B gloads per thread per step; row=(wv<<5)+(j<<4)+(l>>2),
  // lds chunk=l&3 (linear); src chunk swizzled: (l&3)^((row>>1)&3)=(l&3)^((l>>3)&3)
  const int schk = ((lane & 3) ^ ((lane >> 3) & 3)) << 3;  // elem offset
  const unsigned short* aptr[2];
  const unsigned short* bptr[2];
  int amsk[2];
#pragma unroll
  for (int j = 0; j < 2; ++j) {
    int r = (wv << 5) + (j << 4) + (lane >> 2);  // 0..255
    int gm = gm0 + r;
    int lm = gm - mbase;
    int hw = lm & HWm1;
    int hj = hw >> logW, wj = hw & Wm1;
    aptr[j] = xin + ((size_t)gm << 8) + schk;
    bptr[j] = wt + ((size_t)r << 8) + schk;
    bool hm = hj > 0, hp = hj < H - 1, wlo = wj > 0, whi = wj < W - 1;
    int m = 0;
#pragma unroll
    for (int kk = 0; kk < 9; ++kk) {
      int dy = kk / 3 - 1, dxv = kk % 3 - 1;
      bool ok = (dy < 0 ? hm : (dy > 0 ? hp : true)) &&
                (dxv < 0 ? wlo : (dxv > 0 ? whi : true));
      m |= (ok ? 1 : 0) << kk;
    }
    amsk[j] = m;
  }
  const int sdst = ((wv << 5) << 5);  // wave A region base, elems (+j<<9)

  f32x4 acc[8][4];
#pragma unroll
  for (int i = 0; i < 8; ++i)
#pragma unroll
    for (int j = 0; j < 4; ++j) acc[i][j] = (f32x4){0.f, 0.f, 0.f, 0.f};

  const int l15 = lane & 15;
  const int arow0 = (wm << 7) + l15;
  const int brow0 = (wn << 6) + l15;
  const int achk = (((lane >> 4) ^ ((lane >> 1) & 3)) << 4);  // byte offset
  const unsigned pbase = lds_addr(pool);
  const unsigned abase = pbase + (arow0 << 6) + achk;          // + (c<<14)
  const unsigned bbase = pbase + 65536 + (brow0 << 6) + achk;  // + (c<<14)

  // ---- prologue: stage steps 0,1,2 (ich=0, kk=0,1,2) into bufs 0,1,2
  {
    const int m0o = -((W + 1) << 8), m1o = -(W << 8), m2o = -((W - 1) << 8);
#pragma unroll
    for (int j = 0; j < 2; ++j) {
      gload_lds16((amsk[j] & 1) ? (aptr[j] + m0o) : zp,
                  pool + sdst + (j << 9));
      gload_lds16(bptr[j], pool + 32768 + sdst + (j << 9));
    }
#pragma unroll
    for (int j = 0; j < 2; ++j) {
      gload_lds16(((amsk[j] >> 1) & 1) ? (aptr[j] + m1o) : zp,
                  pool + 8192 + sdst + (j << 9));
      gload_lds16(bptr[j] + 65536, pool + 32768 + 8192 + sdst + (j << 9));
    }
#pragma unroll
    for (int j = 0; j < 2; ++j) {
      gload_lds16(((amsk[j] >> 2) & 1) ? (aptr[j] + m2o) : zp,
                  pool + 16384 + sdst + (j << 9));
      gload_lds16(bptr[j] + 131072, pool + 32768 + 16384 + sdst + (j << 9));
    }
  }
  asm volatile("s_waitcnt vmcnt(8)");  // step-0 stage landed

  // stage-target trackers (target = step tt+3; start at 3: ich=0,kk=3)
  int kk3 = 3;
  int mo3 = -256;     // tap (dy=0,dx=-1), elems
  int bo3 = 3 << 16;  // kk3*65536
  int so3 = 0;        // ich3*32

#pragma unroll 1
  for (int tt = 0; tt < 72; ++tt) {
    __builtin_amdgcn_s_barrier();   // buffer (tt&3) staged & block-visible
    const int c = tt & 3;
    const int sb = (tt + 3) & 3;
    const unsigned ava = abase + (c << 14);
    const unsigned bva = bbase + (c << 14);
    f16x8 a0, a1, a2, a3, a4, a5, a6, a7, b0, b1, b2, b3;

    // g1: a0-3 + b0-3 (8 reads)
    DSR(a0, ava, "0");
    DSR(a1, ava, "1024");
    DSR(a2, ava, "2048");
    DSR(a3, ava, "3072");
    DSR(b0, bva, "0");
    DSR(b1, bva, "1024");
    DSR(b2, bva, "2048");
    DSR(b3, bva, "3072");
    // g2: a4-7 (4 reads)
    DSR(a4, ava, "4096");
    DSR(a5, ava, "5120");
    DSR(a6, ava, "6144");
    DSR(a7, ava, "7168");
    // stage step tt+3 into buffer sb (4 gloads)
    if (tt < 69) {
#pragma unroll
      for (int j = 0; j < 2; ++j) {
        const unsigned short* g =
            ((amsk[j] >> kk3) & 1) ? (aptr[j] + mo3 + so3) : zp;
        gload_lds16(g, pool + (sb << 13) + sdst + (j << 9));
      }
#pragma unroll
      for (int j = 0; j < 2; ++j)
        gload_lds16(bptr[j] + bo3 + so3,
                    pool + 32768 + (sb << 13) + sdst + (j << 9));
      // advance trackers (wave-uniform)
      kk3++;
      mo3 += 256;
      bo3 += 65536;
      if (kk3 == 9) {
        kk3 = 0;
        so3 += 32;
        mo3 = -((W + 1) << 8);
        bo3 = 0;
      } else if (kk3 == 3 || kk3 == 6) {
        mo3 += (W - 3) << 8;
      }
    }

    // burst1: needs g1 (g2's 4 outstanding)
    asm volatile("s_waitcnt lgkmcnt(4)");
    __builtin_amdgcn_sched_barrier(0);
    __builtin_amdgcn_s_setprio(1);
    acc[0][0] = __builtin_amdgcn_mfma_f32_16x16x32_f16(a0, b0, acc[0][0], 0, 0, 0);
    acc[0][1] = __builtin_amdgcn_mfma_f32_16x16x32_f16(a0, b1, acc[0][1], 0, 0, 0);
    acc[0][2] = __builtin_amdgcn_mfma_f32_16x16x32_f16(a0, b2, acc[0][2], 0, 0, 0);
    acc[0][3] = __builtin_amdgcn_mfma_f32_16x16x32_f16(a0, b3, acc[0][3], 0, 0, 0);
    acc[1][0] = __builtin_amdgcn_mfma_f32_16x16x32_f16(a1, b0, acc[1][0], 0, 0, 0);
    acc[1][1] = __builtin_amdgcn_mfma_f32_16x16x32_f16(a1, b1, acc[1][1], 0, 0, 0);
    acc[1][2] = __builtin_amdgcn_mfma_f32_16x16x32_f16(a1, b2, acc[1][2], 0, 0, 0);
    acc[1][3] = __builtin_amdgcn_mfma_f32_16x16x32_f16(a1, b3, acc[1][3], 0, 0, 0);
    acc[2][0] = __builtin_amdgcn_mfma_f32_16x16x32_f16(a2, b0, acc[2][0], 0, 0, 0);
    acc[2][1] = __builtin_amdgcn_mfma_f32_16x16x32_f16(a2, b1, acc[2][1], 0, 0, 0);
    acc[2][2] = __builtin_amdgcn_mfma_f32_16x16x32_f16(a2, b2, acc[2][2], 0, 0, 0);
    acc[2][3] = __builtin_amdgcn_mfma_f32_16x16x32_f16(a2, b3, acc[2][3], 0, 0, 0);
    acc[3][0] = __builtin_amdgcn_mfma_f32_16x16x32_f16(a3, b0, acc[3][0], 0, 0, 0);
    acc[3][1] = __builtin_amdgcn_mfma_f32_16x16x32_f16(a3, b1, acc[3][1], 0, 0, 0);
    acc[3][2] = __builtin_amdgcn_mfma_f32_16x16x32_f16(a3, b2, acc[3][2], 0, 0, 0);
    acc[3][3] = __builtin_amdgcn_mfma_f32_16x16x32_f16(a3, b3, acc[3][3], 0, 0, 0);
    __builtin_amdgcn_s_setprio(0);

    // burst2: needs g2 (all reads of buffer c retired after this)
    asm volatile("s_waitcnt lgkmcnt(0)");
    __builtin_amdgcn_sched_barrier(0);
    __builtin_amdgcn_s_setprio(1);
    acc[4][0] = __builtin_amdgcn_mfma_f32_16x16x32_f16(a4, b0, acc[4][0], 0, 0, 0);
    acc[4][1] = __builtin_amdgcn_mfma_f32_16x16x32_f16(a4, b1, acc[4][1], 0, 0, 0);
    acc[4][2] = __builtin_amdgcn_mfma_f32_16x16x32_f16(a4, b2, acc[4][2], 0, 0, 0);
    acc[4][3] = __builtin_amdgcn_mfma_f32_16x16x32_f16(a4, b3, acc[4][3], 0, 0, 0);
    acc[5][0] = __builtin_amdgcn_mfma_f32_16x16x32_f16(a5, b0, acc[5][0], 0, 0, 0);
    acc[5][1] = __builtin_amdgcn_mfma_f32_16x16x32_f16(a5, b1, acc[5][1], 0, 0, 0);
    acc[5][2] = __builtin_amdgcn_mfma_f32_16x16x32_f16(a5, b2, acc[5][2], 0, 0, 0);
    acc[5][3] = __builtin_amdgcn_mfma_f32_16x16x32_f16(a5, b3, acc[5][3], 0, 0, 0);
    acc[6][0] = __builtin_amdgcn_mfma_f32_16x16x32_f16(a6, b0, acc[6][0], 0, 0, 0);
    acc[6][1] = __builtin_amdgcn_mfma_f32_16x16x32_f16(a6, b1, acc[6][1], 0, 0, 0);
    acc[6][2] = __builtin_amdgcn_mfma_f32_16x16x32_f16(a6, b2, acc[6][2], 0, 0, 0);
    acc[6][3] = __builtin_amdgcn_mfma_f32_16x16x32_f16(a6, b3, acc[6][3], 0, 0, 0);
    acc[7][0] = __builtin_amdgcn_mfma_f32_16x16x32_f16(a7, b0, acc[7][0], 0, 0, 0);
    acc[7][1] = __builtin_amdgcn_mfma_f32_16x16x32_f16(a7, b1, acc[7][1], 0, 0, 0);
    acc[7][2] = __builtin_amdgcn_mfma_f32_16x16x32_f16(a7, b2, acc[7][2], 0, 0, 0);
    acc[7][3] = __builtin_amdgcn_mfma_f32_16x16x32_f16(a7, b3, acc[7][3], 0, 0, 0);
    __builtin_amdgcn_s_setprio(0);

    // counted VMEM wait: keep stages(t+2,t+3) in flight
    if (tt < 69)      asm volatile("s_waitcnt vmcnt(8)");
    else if (tt == 69) asm volatile("s_waitcnt vmcnt(4)");
    else               asm volatile("s_waitcnt vmcnt(0)");
  }
  __syncthreads();  // all reads retired before epilogue overwrites pool

  // ---- epilogue: acc -> pool[256][256] fp16 (bias+relu) -> 256B/thread out
  {
    const int eg = (lane >> 4) << 2;
    const int el = lane & 15;
#pragma unroll
    for (int nf = 0; nf < 4; ++nf) {
      float bi = bias[(wn << 6) + (nf << 4) + el];
#pragma unroll
      for (int mf = 0; mf < 8; ++mf)
#pragma unroll
        for (int r = 0; r < 4; ++r) {
          int wrow = (wm << 7) + (mf << 4) + eg + r;
          pool[(wrow << 8) + (wn << 6) + (nf << 4) + el] =
              f2h(fmaxf(acc[mf][nf][r] + bi, 0.0f));
        }
    }
  }
  __syncthreads();
  {
    const int row = t >> 1;
    const int half = t & 1;
    const unsigned short* src = pool + (row << 8) + (half << 7);
    unsigned short* dst = yout + ((size_t)(gm0 + row) << 8) + (half << 7);
#pragma unroll
    for (int q = 0; q < 16; ++q)
      reinterpret_cast<uint4*>(dst)[q] =
          reinterpret_cast<const uint4*>(src)[q];
  }
}

// -------------------------------------------- bbox(20)+conf(4) head -> hbuf
__global__ __launch_bounds__(256) void head24_mfma(
    const unsigned short* __restrict__ t2,  // group-local rows
    const unsigned short* __restrict__ wh,
    const float* __restrict__ regb, const float* __restrict__ confb,
    float* __restrict__ hbuf) {             // group-local rows
  const int t = threadIdx.x, lane = t & 63, wv = t >> 6;
  const int rowb = blockIdx.x * 256 + wv * 64;
  const int kgrp = (lane >> 4) << 3;
  const int l15 = lane & 15;
  f32x4 acc[4][2];
#pragma unroll
  for (int i = 0; i < 4; ++i)
#pragma unroll
    for (int j = 0; j < 2; ++j) acc[i][j] = (f32x4){0.f, 0.f, 0.f, 0.f};
#pragma unroll
  for (int k0 = 0; k0 < 256; k0 += 32) {
    f16x8 a[4], b[2];
#pragma unroll
    for (int mf = 0; mf < 4; ++mf)
      a[mf] = *reinterpret_cast<const f16x8*>(
          t2 + (((size_t)(rowb + (mf << 4) + l15)) << 8) + k0 + kgrp);
#pragma unroll
    for (int nf = 0; nf < 2; ++nf)
      b[nf] = *reinterpret_cast<const f16x8*>(
          wh + (size_t)(((nf << 4) + l15) << 8) + k0 + kgrp);
#pragma unroll
    for (int mf = 0; mf < 4; ++mf)
#pragma unroll
      for (int nf = 0; nf < 2; ++nf)
        acc[mf][nf] = __builtin_amdgcn_mfma_f32_16x16x32_f16(
            a[mf], b[nf], acc[mf][nf], 0, 0, 0);
  }
#pragma unroll
  for (int nf = 0; nf < 2; ++nf) {
    int c = (nf << 4) + l15;
    if (c < 24) {
      float bi = (c < 20) ? regb[c] : confb[c - 20];
#pragma unroll
      for (int mf = 0; mf < 4; ++mf)
#pragma unroll
        for (int r = 0; r < 4; ++r) {
          int m = rowb + (mf << 4) + ((lane >> 4) << 2) + r;
          hbuf[(size_t)m * 24 + c] = acc[mf][nf][r] + bi;
        }
    }
  }
}

// ------------------------------------------- cls head + sigmoid*sigmoid out
__global__ __launch_bounds__(256) void cls_scores(
    const unsigned short* __restrict__ t2,  // absolute rows (ws base)
    const unsigned short* __restrict__ wcw,
    const float* __restrict__ clsb,
    const float* __restrict__ hbuf,         // absolute rows
    float* __restrict__ outs, int gm_base) {
  const int t = threadIdx.x, lane = t & 63, wv = t >> 6;
  const int gm0 = gm_base + blockIdx.x * 256;
  int logW, mbase, lvl_off;
  if (gm0 < 131072) { logW = 7; mbase = 0; lvl_off = 0; }
  else if (gm0 < 163840) { logW = 6; mbase = 131072; lvl_off = 65536; }
  else if (gm0 < 172032) { logW = 5; mbase = 163840; lvl_off = 81920; }
  else if (gm0 < 174080) { logW = 4; mbase = 172032; lvl_off = 86016; }
  else { logW = 3; mbase = 174080; lvl_off = 87040; }
  const int logHW = 2 * logW, HWm1 = (1 << logHW) - 1;
  const int rowb = gm0 + wv * 64;
  const int kgrp = (lane >> 4) << 3;
  const int l15 = lane & 15;
  f32x4 acc[4][4];
#pragma unroll
  for (int i = 0; i < 4; ++i)
#pragma unroll
    for (int j = 0; j < 4; ++j) acc[i][j] = (f32x4){0.f, 0.f, 0.f, 0.f};
#pragma unroll
  for (int k0 = 0; k0 < 256; k0 += 32) {
    f16x8 a[4], b[4];
#pragma unroll
    for (int mf = 0; mf < 4; ++mf)
      a[mf] = *reinterpret_cast<const f16x8*>(
          t2 + (((size_t)(rowb + (mf << 4) + l15)) << 8) + k0 + kgrp);
#pragma unroll
    for (int nf = 0; nf < 4; ++nf)
      b[nf] = *reinterpret_cast<const f16x8*>(
          wcw + (size_t)(((nf << 4) + l15) << 8) + k0 + kgrp);
#pragma unroll
    for (int mf = 0; mf < 4; ++mf)
#pragma unroll
      for (int nf = 0; nf < 4; ++nf)
        acc[mf][nf] = __builtin_amdgcn_mfma_f32_16x16x32_f16(
            a[mf], b[nf], acc[mf][nf], 0, 0, 0);
  }
#pragma unroll
  for (int nf = 0; nf < 4; ++nf) {
    int c = (nf << 4) + l15;
    if (c < 60) {
      int ai = c / 15, ci = c - ai * 15;
      float bi = clsb[c];
#pragma unroll
      for (int mf = 0; mf < 4; ++mf)
#pragma unroll
        for (int r = 0; r < 4; ++r) {
          int m = rowb + (mf << 4) + ((lane >> 4) << 2) + r;
          float logit = acc[mf][nf][r] + bi;
          float conf = hbuf[(size_t)m * 24 + 20 + ai];
          float sc = sigmf(logit) * sigmf(conf);
          int lm = m - mbase;
          int b = lm >> logHW;
          int hw = lm & HWm1;
          int loc = lvl_off + (hw << 2) + ai;
          outs[(size_t)b * 1309440 + (size_t)loc * 15 + ci] = sc;
        }
    }
  }
}

// ------------------------------------------------- rbox decode, all levels
__global__ __launch_bounds__(256) void decode_all(
    const float* __restrict__ hbuf, float* __restrict__ outb) {
  int tid = blockIdx.x * 256 + threadIdx.x;
  if (tid >= 174592 * 4) return;
  int m = tid >> 2, a = tid & 3;
  int logW, mbase, lvl_off;
  float stride;
  if (m < 131072) { logW = 7; mbase = 0; lvl_off = 0; stride = 8.f; }
  else if (m < 163840) { logW = 6; mbase = 131072; lvl_off = 65536; stride = 16.f; }
  else if (m < 172032) { logW = 5; mbase = 163840; lvl_off = 81920; stride = 32.f; }
  else if (m < 174080) { logW = 4; mbase = 172032; lvl_off = 86016; stride = 64.f; }
  else { logW = 3; mbase = 174080; lvl_off = 87040; stride = 128.f; }
  const int logHW = 2 * logW;
  const float ANG[4] = {-0.39269908169872414f, 0.39269908169872414f,
                        1.1780972450961724f, 1.9634954084936207f};
  const float* d = hbuf + (size_t)m * 24 + a * 5;
  float dx = d[0], dy = d[1], dw = d[2], dh = d[3], da = d[4];
  int lm = m - mbase;
  int b = lm >> logHW, hw = lm & ((1 << logHW) - 1);
  int h = hw >> logW, w = hw & ((1 << logW) - 1);
  float ctr = 0.5f * (stride - 1.0f);
  float rx = w * stride + ctr, ry = h * stride + ctr;
  float rw = stride * 1.6329931618554521f;  // 4/sqrt(6)
  float rh = stride * 9.7979589711327124f;  // 4*sqrt(6)
  const float MR = 13.815510557964274f;     // |log(1e-6)|
  dw = fminf(fmaxf(dw, -MR), MR);
  dh = fminf(fmaxf(dh, -MR), MR);
  float gx = dx * rw + rx;
  float gy = dy * rh + ry;
  float gw = rw * expf(dw);
  float gh = rh * expf(dh);
  float v = da + ANG[a] + 0.7853981633974483f;
  float r = fmodf(v, 3.14159265358979323846f);
  if (r < 0.0f) r += 3.14159265358979323846f;
  float ga = r - 0.7853981633974483f;
  int loc = lvl_off + (hw << 2) + a;
  size_t base = (size_t)b * 436480 + (size_t)loc * 5;
  outb[base + 0] = gx;
  outb[base + 1] = gy;
  outb[base + 2] = gw;
  outb[base + 3] = gh;
  outb[base + 4] = ga;
}

// ============================================================================
extern "C" void kernel_launch(void* const* d_in, const int* in_sizes, int n_in,
                              void* d_out, int out_size, void* d_ws,
                              size_t ws_size, hipStream_t stream) {
  const float* feats[5];
  for (int i = 0; i < 5; ++i) feats[i] = (const float*)d_in[i];
  const float* reg_w0 = (const float*)d_in[5];
  const float* reg_b0 = (const float*)d_in[6];
  const float* reg_w1 = (const float*)d_in[7];
  const float* reg_b1 = (const float*)d_in[8];
  const float* cls_w0 = (const float*)d_in[9];
  const float* cls_b0 = (const float*)d_in[10];
  const float* cls_w1 = (const float*)d_in[11];
  const float* cls_b1 = (const float*)d_in[12];
  const float* reg_head_w = (const float*)d_in[13];
  const float* reg_head_b = (const float*)d_in[14];
  const float* cls_head_w = (const float*)d_in[15];
  const float* cls_head_b = (const float*)d_in[16];
  const float* conf_w = (const float*)d_in[17];
  const float* conf_b = (const float*)d_in[18];

  unsigned short* ws = (unsigned short*)d_ws;
  unsigned short* t1r = ws + 44695552ull;
  unsigned short* t1c = ws + 78249984ull;
  unsigned short* wt4 = ws + 111804416ull;
  unsigned short* wh = ws + 114163712ull;
  unsigned short* wc = ws + 114171904ull;
  unsigned short* zp = ws + 114188288ull;
  float* hbuf_all = (float*)((char*)d_ws + 228376704ull);

  prep_convw<<<9216, 256, 0, stream>>>(reg_w0, reg_w1, cls_w0, cls_w1, wt4);
  prep_small<<<97, 256, 0, stream>>>(cls_head_w, reg_head_w, conf_w, wc, wh,
                                     zp);
  to_nhwc_all<<<2728, 256, 0, stream>>>(feats[0], feats[1], feats[2], feats[3],
                                        feats[4], ws);

  float* scores = (float*)d_out;
  float* boxes = (float*)d_out + SCORES_TOTAL;

  static const int gbase[2] = {0, 131072};
  static const int gM[2] = {131072, 43520};
  for (int g = 0; g < 2; ++g) {
    const int base = gbase[g];
    const int M = gM[g];
    const int nb = M / 256;
    const size_t bofs = ((size_t)base << 8);
    unsigned short* t1r_v = t1r - bofs;  // group-local virtual bases
    unsigned short* t1c_v = t1c - bofs;
    // conv1 both towers in ONE dispatch (grid.y = tower)
    conv256q<<<dim3(nb, 2), 512, 0, stream>>>(
        ws, wt4 + 0ull * 589824, wt4 + 2ull * 589824, reg_b0, cls_b0, zp,
        t1r_v, t1c_v, base);
    conv256q<<<dim3(nb, 1), 512, 0, stream>>>(
        t1r_v, wt4 + 1ull * 589824, wt4 + 1ull * 589824, reg_b1, reg_b1, zp,
        ws, ws, base);
    head24_mfma<<<nb, 256, 0, stream>>>(ws + bofs, wh, reg_head_b, conf_b,
                                        hbuf_all + (size_t)base * 24);
    conv256q<<<dim3(nb, 1), 512, 0, stream>>>(
        t1c_v, wt4 + 3ull * 589824, wt4 + 3ull * 589824, cls_b1, cls_b1, zp,
        ws, ws, base);
    cls_scores<<<nb, 256, 0, stream>>>(ws, wc, cls_head_b, hbuf_all, scores,
                                       base);
  }
  decode_all<<<(174592 * 4 + 255) / 256, 256, 0, stream>>>(hbuf_all, boxes);
}

// Round 18
// 990.067 us; speedup vs baseline: 1.1219x; 1.1219x over previous
//
#include <hip/hip_runtime.h>

// ============================================================================
// RetinaNetHead (S2ANet-style rotated head), MI355X gfx950.
// R18: consolidation. Conv = R16's proven schedule (BK=64, 2 LDS dbuf 128KB,
//   ONE barrier/K-step, counted-lgkm read||MFMA interleave: g1(8) g2(4)
//   stageA | lgkm(4) burst1 | g3(8) stageB | lgkm(8) burst2 | g4(4) |
//   lgkm(4) burst3 | lgkm(0) burst4 | vmcnt(0) bar). R17's 4-buffer BK=32
//   variant REFUTED (178 vs 156 us/conv; conflicts 2x). Kept from R17 only
//   the launch-level conv1 tower merge (grid.y selects tower). conv2c moved
//   before head24 to batch the small head kernels.
// fp32 accum; logits/decode fp32.
//
// Level geometry: rows gm 0..174591; cum={0,131072,163840,172032,174080,174592}
// Workspace (ushort units), same footprint (~245.1MB):
//   [0) feats NHWC fp16 (reused as t2) | [44,695,552) t1r | [78,249,984) t1c
//   [111,804,416) conv w 4x[9][256][256] | [114,163,712) wh | [114,171,904) wc
//   [114,188,288) zp | byte 228,376,704: hbuf fp32 [174592][24]
// ============================================================================

typedef __attribute__((ext_vector_type(8))) _Float16 f16x8;
typedef __attribute__((ext_vector_type(4))) float f32x4;

#define SCORES_TOTAL 10475520ull  // 8*87296*15

__device__ __forceinline__ unsigned short f2h(float f) {
  union { _Float16 h; unsigned short u; } x;
  x.h = (_Float16)f;
  return x.u;
}

__device__ __forceinline__ float sigmf(float x) {
  return 1.0f / (1.0f + expf(-x));
}

__device__ __forceinline__ void gload_lds16(const unsigned short* g,
                                            unsigned short* l) {
  __builtin_amdgcn_global_load_lds(
      (const __attribute__((address_space(1))) unsigned int*)g,
      (__attribute__((address_space(3))) unsigned int*)l, 16, 0, 0);
}

__device__ __forceinline__ unsigned lds_addr(const void* p) {
  return (unsigned)(size_t)(const __attribute__((address_space(3))) char*)p;
}

// clobber-free ds_read_b128 with literal byte offset (volatile keeps order)
#define DSR(d, va, off) \
  asm volatile("ds_read_b128 %0, %1 offset:" off : "=v"(d) : "v"(va))

__device__ __forceinline__ void lvl_lookup(int gm, int& logW, int& mbase) {
  if (gm < 131072) { logW = 7; mbase = 0; }
  else if (gm < 163840) { logW = 6; mbase = 131072; }
  else if (gm < 172032) { logW = 5; mbase = 163840; }
  else if (gm < 174080) { logW = 4; mbase = 172032; }
  else { logW = 3; mbase = 174080; }
}

// ---------------------------------------------------------------- weight prep
__global__ __launch_bounds__(256) void prep_convw(
    const float* __restrict__ w0, const float* __restrict__ w1,
    const float* __restrict__ w2, const float* __restrict__ w3,
    unsigned short* __restrict__ wtout) {
  int g = blockIdx.x * 256 + threadIdx.x;  // < 4*589824
  int q = g >> 16;
  int wsel = q / 9;
  int kk = q - wsel * 9;
  int r = g & 65535;
  int oc = r >> 8, ic = r & 255;
  const float* src = (wsel == 0) ? w0 : (wsel == 1) ? w1 : (wsel == 2) ? w2 : w3;
  float v = src[(size_t)(oc * 256 + ic) * 9 + kk];
  wtout[(size_t)wsel * 589824 + (size_t)((kk << 8) + oc) * 256 + ic] = f2h(v);
}

__global__ __launch_bounds__(256) void prep_small(
    const float* __restrict__ clsh, const float* __restrict__ regh,
    const float* __restrict__ confw,
    unsigned short* __restrict__ wc, unsigned short* __restrict__ wh,
    unsigned short* __restrict__ zp) {
  int g = blockIdx.x * 256 + threadIdx.x;
  if (g < 16384) {
    int row = g >> 8, ic = g & 255;
    float v = (row < 60) ? clsh[row * 256 + ic] : 0.0f;
    wc[g] = f2h(v);
  } else if (g < 24576) {
    int gg = g - 16384;
    int row = gg >> 8, ic = gg & 255;
    float v = 0.0f;
    if (row < 20) v = regh[row * 256 + ic];
    else if (row < 24) v = confw[(row - 20) * 256 + ic];
    wh[gg] = f2h(v);
  } else if (g < 24640) {
    zp[g - 24576] = 0;
  }
}

// ------------------------------- NCHW fp32 -> NHWC fp16, all levels merged
__global__ __launch_bounds__(256) void to_nhwc_all(
    const float* __restrict__ f0, const float* __restrict__ f1,
    const float* __restrict__ f2, const float* __restrict__ f3,
    const float* __restrict__ f4, unsigned short* __restrict__ out) {
  __shared__ unsigned short L[64][258];
  const int t = threadIdx.x;
  const int gm0 = blockIdx.x * 64;
  int logW, mbase;
  const float* in;
  if (gm0 < 131072) { logW = 7; mbase = 0; in = f0; }
  else if (gm0 < 163840) { logW = 6; mbase = 131072; in = f1; }
  else if (gm0 < 172032) { logW = 5; mbase = 163840; in = f2; }
  else if (gm0 < 174080) { logW = 4; mbase = 172032; in = f3; }
  else { logW = 3; mbase = 174080; in = f4; }
  const int logHW = 2 * logW;
  const int HW = 1 << logHW;
  const int lm0 = gm0 - mbase;
  const int b = lm0 >> logHW;
  const int hw0 = lm0 & (HW - 1);
#pragma unroll
  for (int it = 0; it < 16; ++it) {
    int c = it * 16 + (t >> 4);
    int j4 = (t & 15) * 4;
    float4 v = *reinterpret_cast<const float4*>(
        in + (size_t)(b * 256 + c) * HW + hw0 + j4);
    L[j4 + 0][c] = f2h(v.x);
    L[j4 + 1][c] = f2h(v.y);
    L[j4 + 2][c] = f2h(v.z);
    L[j4 + 3][c] = f2h(v.w);
  }
  __syncthreads();
#pragma unroll
  for (int it = 0; it < 16; ++it) {
    int j = it * 4 + (t >> 6);
    int c4 = (t & 63) * 4;
    unsigned v0 = (unsigned)L[j][c4 + 0] | ((unsigned)L[j][c4 + 1] << 16);
    unsigned v1 = (unsigned)L[j][c4 + 2] | ((unsigned)L[j][c4 + 3] << 16);
    uint2 v = make_uint2(v0, v1);
    *reinterpret_cast<uint2*>(out + ((size_t)(gm0 + j) << 8) + c4) = v;
  }
}

// ------------------- conv3x3: 256Mx256N tile, BK=64, 1-barrier K-step
// grid.y selects tower (A vs B weight/bias/out); conv2 passes same twice.
__global__ __launch_bounds__(512, 2) void conv256(
    const unsigned short* __restrict__ xin,   // virtual base: rows at abs gm
    const unsigned short* __restrict__ wtA,
    const unsigned short* __restrict__ wtB,
    const float* __restrict__ biasA, const float* __restrict__ biasB,
    const unsigned short* __restrict__ zp,
    unsigned short* __restrict__ outA, unsigned short* __restrict__ outB,
    int gm_base) {
  __shared__ unsigned short pool[65536];      // A 2x32KB | B 2x32KB (128KB)
  const int sel = blockIdx.y;
  const unsigned short* wt = sel ? wtB : wtA;
  const float* bias = sel ? biasB : biasA;
  unsigned short* yout = sel ? outB : outA;

  const int t = threadIdx.x;
  const int lane = t & 63;
  const int wv = t >> 6;       // 0..7
  const int wm = wv >> 2;      // 0..1
  const int wn = wv & 3;       // 0..3
  const int gm0 = gm_base + blockIdx.x * 256;
  int logW, mbase;
  lvl_lookup(gm0, logW, mbase);
  const int logHW = 2 * logW;
  const int H = 1 << logW, W = H;
  const int HWm1 = (1 << logHW) - 1, Wm1 = W - 1;

  // ---- staging precompute (4 A-slots + 4 B-slots per thread, 16B each)
  const int schk = ((lane & 7) ^ ((lane >> 3) & 7)) << 3;  // elem offset
  int hj[4], wj[4];
  const unsigned short* aptr[4];
  const unsigned short* bptr[4];
#pragma unroll
  for (int i = 0; i < 4; ++i) {
    int r = (wv << 5) + (i << 3) + (lane >> 3);  // 0..255 (row / oc)
    int gm = gm0 + r;
    int lm = gm - mbase;
    int hw = lm & HWm1;
    hj[i] = hw >> logW;
    wj[i] = hw & Wm1;
    aptr[i] = xin + ((size_t)gm << 8) + schk;
    bptr[i] = wt + ((size_t)r << 8) + schk;
  }

  f32x4 acc[8][4];
#pragma unroll
  for (int i = 0; i < 8; ++i)
#pragma unroll
    for (int j = 0; j < 4; ++j) acc[i][j] = (f32x4){0.f, 0.f, 0.f, 0.f};

  const int l15 = lane & 15;
  const int arow0 = (wm << 7) + l15;  // A row base (within 256)
  const int brow0 = (wn << 6) + l15;  // B row base (oc)
  int achkb[2];
#pragma unroll
  for (int ks = 0; ks < 2; ++ks)
    achkb[ks] = ((((ks << 2) + (lane >> 4)) ^ (lane & 7)) << 4);  // bytes

  // LDS byte addresses for asm ds_read (buffer 0 initially; XOR 32768 flips)
  const unsigned pbase = lds_addr(pool);
  unsigned ava0 = pbase + (arow0 << 7) + achkb[0];
  unsigned ava1 = pbase + (arow0 << 7) + achkb[1];
  unsigned bva0 = pbase + 65536 + (brow0 << 7) + achkb[0];
  unsigned bva1 = pbase + 65536 + (brow0 << 7) + achkb[1];

  // phase p of 36: icq = p/9 (ic0 = icq*64), kk = p%9 (tap)
  auto STAGE_A = [&](int p, int bsel) {
    int icq = p / 9;
    int kk = p - icq * 9;
    int k3 = kk / 3;
    int dy = k3 - 1, dxv = kk - k3 * 3 - 1;
    int moff = ((dy << logW) + dxv) << 8;
    int ico = icq << 6;
    unsigned short* dst = pool + (bsel << 14) + (wv << 11);
#pragma unroll
    for (int i = 0; i < 4; ++i) {
      bool valid = ((unsigned)(hj[i] + dy) < (unsigned)H) &
                   ((unsigned)(wj[i] + dxv) < (unsigned)W);
      const unsigned short* g = valid ? (aptr[i] + moff + ico) : zp;
      gload_lds16(g, dst + (i << 9));
    }
  };
  auto STAGE_B = [&](int p, int bsel) {
    int icq = p / 9;
    int kk = p - icq * 9;
    int boff = (kk << 16) + (icq << 6);
    unsigned short* dst = pool + 32768 + (bsel << 14) + (wv << 11);
#pragma unroll
    for (int i = 0; i < 4; ++i)
      gload_lds16(bptr[i] + boff, dst + (i << 9));
  };

  // ---- prologue: stage K-step 0 fully into buffer 0
  STAGE_A(0, 0);
  STAGE_B(0, 0);
  asm volatile("s_waitcnt vmcnt(0)");
  __builtin_amdgcn_s_barrier();

#pragma unroll 1
  for (int tt = 0; tt < 36; ++tt) {
    const int nb = (tt & 1) ^ 1;
    f16x8 a0, a1, a2, a3, a4, a5, a6, a7;
    f16x8 b00, b01, b02, b03, b10, b11, b12, b13;

    // ---- g1: ks0 a0-3 + b0 (8 reads)
    DSR(a0, ava0, "0");
    DSR(a1, ava0, "2048");
    DSR(a2, ava0, "4096");
    DSR(a3, ava0, "6144");
    DSR(b00, bva0, "0");
    DSR(b01, bva0, "2048");
    DSR(b02, bva0, "4096");
    DSR(b03, bva0, "6144");
    // ---- g2: ks0 a4-7 (4 reads)
    DSR(a4, ava0, "8192");
    DSR(a5, ava0, "10240");
    DSR(a6, ava0, "12288");
    DSR(a7, ava0, "14336");
    if (tt < 35) STAGE_A(tt + 1, nb);

    // ---- burst1: needs g1 (g2 may remain outstanding)
    asm volatile("s_waitcnt lgkmcnt(4)");
    __builtin_amdgcn_sched_barrier(0);
    __builtin_amdgcn_s_setprio(1);
    acc[0][0] = __builtin_amdgcn_mfma_f32_16x16x32_f16(a0, b00, acc[0][0], 0, 0, 0);
    acc[0][1] = __builtin_amdgcn_mfma_f32_16x16x32_f16(a0, b01, acc[0][1], 0, 0, 0);
    acc[0][2] = __builtin_amdgcn_mfma_f32_16x16x32_f16(a0, b02, acc[0][2], 0, 0, 0);
    acc[0][3] = __builtin_amdgcn_mfma_f32_16x16x32_f16(a0, b03, acc[0][3], 0, 0, 0);
    acc[1][0] = __builtin_amdgcn_mfma_f32_16x16x32_f16(a1, b00, acc[1][0], 0, 0, 0);
    acc[1][1] = __builtin_amdgcn_mfma_f32_16x16x32_f16(a1, b01, acc[1][1], 0, 0, 0);
    acc[1][2] = __builtin_amdgcn_mfma_f32_16x16x32_f16(a1, b02, acc[1][2], 0, 0, 0);
    acc[1][3] = __builtin_amdgcn_mfma_f32_16x16x32_f16(a1, b03, acc[1][3], 0, 0, 0);
    acc[2][0] = __builtin_amdgcn_mfma_f32_16x16x32_f16(a2, b00, acc[2][0], 0, 0, 0);
    acc[2][1] = __builtin_amdgcn_mfma_f32_16x16x32_f16(a2, b01, acc[2][1], 0, 0, 0);
    acc[2][2] = __builtin_amdgcn_mfma_f32_16x16x32_f16(a2, b02, acc[2][2], 0, 0, 0);
    acc[2][3] = __builtin_amdgcn_mfma_f32_16x16x32_f16(a2, b03, acc[2][3], 0, 0, 0);
    acc[3][0] = __builtin_amdgcn_mfma_f32_16x16x32_f16(a3, b00, acc[3][0], 0, 0, 0);
    acc[3][1] = __builtin_amdgcn_mfma_f32_16x16x32_f16(a3, b01, acc[3][1], 0, 0, 0);
    acc[3][2] = __builtin_amdgcn_mfma_f32_16x16x32_f16(a3, b02, acc[3][2], 0, 0, 0);
    acc[3][3] = __builtin_amdgcn_mfma_f32_16x16x32_f16(a3, b03, acc[3][3], 0, 0, 0);
    __builtin_amdgcn_s_setprio(0);

    // ---- g3: ks1 a0-3 + b1 (8 reads), issued DURING burst window
    DSR(a0, ava1, "0");
    DSR(a1, ava1, "2048");
    DSR(a2, ava1, "4096");
    DSR(a3, ava1, "6144");
    DSR(b10, bva1, "0");
    DSR(b11, bva1, "2048");
    DSR(b12, bva1, "4096");
    DSR(b13, bva1, "6144");
    if (tt < 35) STAGE_B(tt + 1, nb);

    // ---- burst2: needs g2 (g3's 8 may remain outstanding)
    asm volatile("s_waitcnt lgkmcnt(8)");
    __builtin_amdgcn_sched_barrier(0);
    __builtin_amdgcn_s_setprio(1);
    acc[4][0] = __builtin_amdgcn_mfma_f32_16x16x32_f16(a4, b00, acc[4][0], 0, 0, 0);
    acc[4][1] = __builtin_amdgcn_mfma_f32_16x16x32_f16(a4, b01, acc[4][1], 0, 0, 0);
    acc[4][2] = __builtin_amdgcn_mfma_f32_16x16x32_f16(a4, b02, acc[4][2], 0, 0, 0);
    acc[4][3] = __builtin_amdgcn_mfma_f32_16x16x32_f16(a4, b03, acc[4][3], 0, 0, 0);
    acc[5][0] = __builtin_amdgcn_mfma_f32_16x16x32_f16(a5, b00, acc[5][0], 0, 0, 0);
    acc[5][1] = __builtin_amdgcn_mfma_f32_16x16x32_f16(a5, b01, acc[5][1], 0, 0, 0);
    acc[5][2] = __builtin_amdgcn_mfma_f32_16x16x32_f16(a5, b02, acc[5][2], 0, 0, 0);
    acc[5][3] = __builtin_amdgcn_mfma_f32_16x16x32_f16(a5, b03, acc[5][3], 0, 0, 0);
    acc[6][0] = __builtin_amdgcn_mfma_f32_16x16x32_f16(a6, b00, acc[6][0], 0, 0, 0);
    acc[6][1] = __builtin_amdgcn_mfma_f32_16x16x32_f16(a6, b01, acc[6][1], 0, 0, 0);
    acc[6][2] = __builtin_amdgcn_mfma_f32_16x16x32_f16(a6, b02, acc[6][2], 0, 0, 0);
    acc[6][3] = __builtin_amdgcn_mfma_f32_16x16x32_f16(a6, b03, acc[6][3], 0, 0, 0);
    acc[7][0] = __builtin_amdgcn_mfma_f32_16x16x32_f16(a7, b00, acc[7][0], 0, 0, 0);
    acc[7][1] = __builtin_amdgcn_mfma_f32_16x16x32_f16(a7, b01, acc[7][1], 0, 0, 0);
    acc[7][2] = __builtin_amdgcn_mfma_f32_16x16x32_f16(a7, b02, acc[7][2], 0, 0, 0);
    acc[7][3] = __builtin_amdgcn_mfma_f32_16x16x32_f16(a7, b03, acc[7][3], 0, 0, 0);
    __builtin_amdgcn_s_setprio(0);

    // ---- g4: ks1 a4-7 (4 reads)
    DSR(a4, ava1, "8192");
    DSR(a5, ava1, "10240");
    DSR(a6, ava1, "12288");
    DSR(a7, ava1, "14336");

    // ---- burst3: needs g3 (g4 may remain outstanding)
    asm volatile("s_waitcnt lgkmcnt(4)");
    __builtin_amdgcn_sched_barrier(0);
    __builtin_amdgcn_s_setprio(1);
    acc[0][0] = __builtin_amdgcn_mfma_f32_16x16x32_f16(a0, b10, acc[0][0], 0, 0, 0);
    acc[0][1] = __builtin_amdgcn_mfma_f32_16x16x32_f16(a0, b11, acc[0][1], 0, 0, 0);
    acc[0][2] = __builtin_amdgcn_mfma_f32_16x16x32_f16(a0, b12, acc[0][2], 0, 0, 0);
    acc[0][3] = __builtin_amdgcn_mfma_f32_16x16x32_f16(a0, b13, acc[0][3], 0, 0, 0);
    acc[1][0] = __builtin_amdgcn_mfma_f32_16x16x32_f16(a1, b10, acc[1][0], 0, 0, 0);
    acc[1][1] = __builtin_amdgcn_mfma_f32_16x16x32_f16(a1, b11, acc[1][1], 0, 0, 0);
    acc[1][2] = __builtin_amdgcn_mfma_f32_16x16x32_f16(a1, b12, acc[1][2], 0, 0, 0);
    acc[1][3] = __builtin_amdgcn_mfma_f32_16x16x32_f16(a1, b13, acc[1][3], 0, 0, 0);
    acc[2][0] = __builtin_amdgcn_mfma_f32_16x16x32_f16(a2, b10, acc[2][0], 0, 0, 0);
    acc[2][1] = __builtin_amdgcn_mfma_f32_16x16x32_f16(a2, b11, acc[2][1], 0, 0, 0);
    acc[2][2] = __builtin_amdgcn_mfma_f32_16x16x32_f16(a2, b12, acc[2][2], 0, 0, 0);
    acc[2][3] = __builtin_amdgcn_mfma_f32_16x16x32_f16(a2, b13, acc[2][3], 0, 0, 0);
    acc[3][0] = __builtin_amdgcn_mfma_f32_16x16x32_f16(a3, b10, acc[3][0], 0, 0, 0);
    acc[3][1] = __builtin_amdgcn_mfma_f32_16x16x32_f16(a3, b11, acc[3][1], 0, 0, 0);
    acc[3][2] = __builtin_amdgcn_mfma_f32_16x16x32_f16(a3, b12, acc[3][2], 0, 0, 0);
    acc[3][3] = __builtin_amdgcn_mfma_f32_16x16x32_f16(a3, b13, acc[3][3], 0, 0, 0);
    __builtin_amdgcn_s_setprio(0);

    // ---- burst4: needs g4 (all reads of buffer c retired after this wait)
    asm volatile("s_waitcnt lgkmcnt(0)");
    __builtin_amdgcn_sched_barrier(0);
    __builtin_amdgcn_s_setprio(1);
    acc[4][0] = __builtin_amdgcn_mfma_f32_16x16x32_f16(a4, b10, acc[4][0], 0, 0, 0);
    acc[4][1] = __builtin_amdgcn_mfma_f32_16x16x32_f16(a4, b11, acc[4][1], 0, 0, 0);
    acc[4][2] = __builtin_amdgcn_mfma_f32_16x16x32_f16(a4, b12, acc[4][2], 0, 0, 0);
    acc[4][3] = __builtin_amdgcn_mfma_f32_16x16x32_f16(a4, b13, acc[4][3], 0, 0, 0);
    acc[5][0] = __builtin_amdgcn_mfma_f32_16x16x32_f16(a5, b10, acc[5][0], 0, 0, 0);
    acc[5][1] = __builtin_amdgcn_mfma_f32_16x16x32_f16(a5, b11, acc[5][1], 0, 0, 0);
    acc[5][2] = __builtin_amdgcn_mfma_f32_16x16x32_f16(a5, b12, acc[5][2], 0, 0, 0);
    acc[5][3] = __builtin_amdgcn_mfma_f32_16x16x32_f16(a5, b13, acc[5][3], 0, 0, 0);
    acc[6][0] = __builtin_amdgcn_mfma_f32_16x16x32_f16(a6, b10, acc[6][0], 0, 0, 0);
    acc[6][1] = __builtin_amdgcn_mfma_f32_16x16x32_f16(a6, b11, acc[6][1], 0, 0, 0);
    acc[6][2] = __builtin_amdgcn_mfma_f32_16x16x32_f16(a6, b12, acc[6][2], 0, 0, 0);
    acc[6][3] = __builtin_amdgcn_mfma_f32_16x16x32_f16(a6, b13, acc[6][3], 0, 0, 0);
    acc[7][0] = __builtin_amdgcn_mfma_f32_16x16x32_f16(a7, b10, acc[7][0], 0, 0, 0);
    acc[7][1] = __builtin_amdgcn_mfma_f32_16x16x32_f16(a7, b11, acc[7][1], 0, 0, 0);
    acc[7][2] = __builtin_amdgcn_mfma_f32_16x16x32_f16(a7, b12, acc[7][2], 0, 0, 0);
    acc[7][3] = __builtin_amdgcn_mfma_f32_16x16x32_f16(a7, b13, acc[7][3], 0, 0, 0);
    __builtin_amdgcn_s_setprio(0);

    // ---- K-step end: stages(t+1) drained, single barrier, flip buffers
    asm volatile("s_waitcnt vmcnt(0)");
    __builtin_amdgcn_s_barrier();
    ava0 ^= 32768u;
    ava1 ^= 32768u;
    bva0 ^= 32768u;
    bva1 ^= 32768u;
  }
  __syncthreads();  // full drain before epilogue overwrites pool

  // ---- epilogue: acc -> pool[256][256] fp16 (bias+relu) -> 256B/thread out
  {
    const int eg = (lane >> 4) << 2;
    const int el = lane & 15;
#pragma unroll
    for (int nf = 0; nf < 4; ++nf) {
      float bi = bias[(wn << 6) + (nf << 4) + el];
#pragma unroll
      for (int mf = 0; mf < 8; ++mf)
#pragma unroll
        for (int r = 0; r < 4; ++r) {
          int wrow = (wm << 7) + (mf << 4) + eg + r;
          pool[(wrow << 8) + (wn << 6) + (nf << 4) + el] =
              f2h(fmaxf(acc[mf][nf][r] + bi, 0.0f));
        }
    }
  }
  __syncthreads();
  {
    const int row = t >> 1;
    const int half = t & 1;
    const unsigned short* src = pool + (row << 8) + (half << 7);
    unsigned short* dst = yout + ((size_t)(gm0 + row) << 8) + (half << 7);
#pragma unroll
    for (int q = 0; q < 16; ++q)
      reinterpret_cast<uint4*>(dst)[q] =
          reinterpret_cast<const uint4*>(src)[q];
  }
}

// -------------------------------------------- bbox(20)+conf(4) head -> hbuf
__global__ __launch_bounds__(256) void head24_mfma(
    const unsigned short* __restrict__ t2,  // group-local rows
    const unsigned short* __restrict__ wh,
    const float* __restrict__ regb, const float* __restrict__ confb,
    float* __restrict__ hbuf) {             // group-local rows
  const int t = threadIdx.x, lane = t & 63, wv = t >> 6;
  const int rowb = blockIdx.x * 256 + wv * 64;
  const int kgrp = (lane >> 4) << 3;
  const int l15 = lane & 15;
  f32x4 acc[4][2];
#pragma unroll
  for (int i = 0; i < 4; ++i)
#pragma unroll
    for (int j = 0; j < 2; ++j) acc[i][j] = (f32x4){0.f, 0.f, 0.f, 0.f};
#pragma unroll
  for (int k0 = 0; k0 < 256; k0 += 32) {
    f16x8 a[4], b[2];
#pragma unroll
    for (int mf = 0; mf < 4; ++mf)
      a[mf] = *reinterpret_cast<const f16x8*>(
          t2 + (((size_t)(rowb + (mf << 4) + l15)) << 8) + k0 + kgrp);
#pragma unroll
    for (int nf = 0; nf < 2; ++nf)
      b[nf] = *reinterpret_cast<const f16x8*>(
          wh + (size_t)(((nf << 4) + l15) << 8) + k0 + kgrp);
#pragma unroll
    for (int mf = 0; mf < 4; ++mf)
#pragma unroll
      for (int nf = 0; nf < 2; ++nf)
        acc[mf][nf] = __builtin_amdgcn_mfma_f32_16x16x32_f16(
            a[mf], b[nf], acc[mf][nf], 0, 0, 0);
  }
#pragma unroll
  for (int nf = 0; nf < 2; ++nf) {
    int c = (nf << 4) + l15;
    if (c < 24) {
      float bi = (c < 20) ? regb[c] : confb[c - 20];
#pragma unroll
      for (int mf = 0; mf < 4; ++mf)
#pragma unroll
        for (int r = 0; r < 4; ++r) {
          int m = rowb + (mf << 4) + ((lane >> 4) << 2) + r;
          hbuf[(size_t)m * 24 + c] = acc[mf][nf][r] + bi;
        }
    }
  }
}

// ------------------------------------------- cls head + sigmoid*sigmoid out
__global__ __launch_bounds__(256) void cls_scores(
    const unsigned short* __restrict__ t2,  // absolute rows (ws base)
    const unsigned short* __restrict__ wcw,
    const float* __restrict__ clsb,
    const float* __restrict__ hbuf,         // absolute rows
    float* __restrict__ outs, int gm_base) {
  const int t = threadIdx.x, lane = t & 63, wv = t >> 6;
  const int gm0 = gm_base + blockIdx.x * 256;
  int logW, mbase, lvl_off;
  if (gm0 < 131072) { logW = 7; mbase = 0; lvl_off = 0; }
  else if (gm0 < 163840) { logW = 6; mbase = 131072; lvl_off = 65536; }
  else if (gm0 < 172032) { logW = 5; mbase = 163840; lvl_off = 81920; }
  else if (gm0 < 174080) { logW = 4; mbase = 172032; lvl_off = 86016; }
  else { logW = 3; mbase = 174080; lvl_off = 87040; }
  const int logHW = 2 * logW, HWm1 = (1 << logHW) - 1;
  const int rowb = gm0 + wv * 64;
  const int kgrp = (lane >> 4) << 3;
  const int l15 = lane & 15;
  f32x4 acc[4][4];
#pragma unroll
  for (int i = 0; i < 4; ++i)
#pragma unroll
    for (int j = 0; j < 4; ++j) acc[i][j] = (f32x4){0.f, 0.f, 0.f, 0.f};
#pragma unroll
  for (int k0 = 0; k0 < 256; k0 += 32) {
    f16x8 a[4], b[4];
#pragma unroll
    for (int mf = 0; mf < 4; ++mf)
      a[mf] = *reinterpret_cast<const f16x8*>(
          t2 + (((size_t)(rowb + (mf << 4) + l15)) << 8) + k0 + kgrp);
#pragma unroll
    for (int nf = 0; nf < 4; ++nf)
      b[nf] = *reinterpret_cast<const f16x8*>(
          wcw + (size_t)(((nf << 4) + l15) << 8) + k0 + kgrp);
#pragma unroll
    for (int mf = 0; mf < 4; ++mf)
#pragma unroll
      for (int nf = 0; nf < 4; ++nf)
        acc[mf][nf] = __builtin_amdgcn_mfma_f32_16x16x32_f16(
            a[mf], b[nf], acc[mf][nf], 0, 0, 0);
  }
#pragma unroll
  for (int nf = 0; nf < 4; ++nf) {
    int c = (nf << 4) + l15;
    if (c < 60) {
      int ai = c / 15, ci = c - ai * 15;
      float bi = clsb[c];
#pragma unroll
      for (int mf = 0; mf < 4; ++mf)
#pragma unroll
        for (int r = 0; r < 4; ++r) {
          int m = rowb + (mf << 4) + ((lane >> 4) << 2) + r;
          float logit = acc[mf][nf][r] + bi;
          float conf = hbuf[(size_t)m * 24 + 20 + ai];
          float sc = sigmf(logit) * sigmf(conf);
          int lm = m - mbase;
          int b = lm >> logHW;
          int hw = lm & HWm1;
          int loc = lvl_off + (hw << 2) + ai;
          outs[(size_t)b * 1309440 + (size_t)loc * 15 + ci] = sc;
        }
    }
  }
}

// ------------------------------------------------- rbox decode, all levels
__global__ __launch_bounds__(256) void decode_all(
    const float* __restrict__ hbuf, float* __restrict__ outb) {
  int tid = blockIdx.x * 256 + threadIdx.x;
  if (tid >= 174592 * 4) return;
  int m = tid >> 2, a = tid & 3;
  int logW, mbase, lvl_off;
  float stride;
  if (m < 131072) { logW = 7; mbase = 0; lvl_off = 0; stride = 8.f; }
  else if (m < 163840) { logW = 6; mbase = 131072; lvl_off = 65536; stride = 16.f; }
  else if (m < 172032) { logW = 5; mbase = 163840; lvl_off = 81920; stride = 32.f; }
  else if (m < 174080) { logW = 4; mbase = 172032; lvl_off = 86016; stride = 64.f; }
  else { logW = 3; mbase = 174080; lvl_off = 87040; stride = 128.f; }
  const int logHW = 2 * logW;
  const float ANG[4] = {-0.39269908169872414f, 0.39269908169872414f,
                        1.1780972450961724f, 1.9634954084936207f};
  const float* d = hbuf + (size_t)m * 24 + a * 5;
  float dx = d[0], dy = d[1], dw = d[2], dh = d[3], da = d[4];
  int lm = m - mbase;
  int b = lm >> logHW, hw = lm & ((1 << logHW) - 1);
  int h = hw >> logW, w = hw & ((1 << logW) - 1);
  float ctr = 0.5f * (stride - 1.0f);
  float rx = w * stride + ctr, ry = h * stride + ctr;
  float rw = stride * 1.6329931618554521f;  // 4/sqrt(6)
  float rh = stride * 9.7979589711327124f;  // 4*sqrt(6)
  const float MR = 13.815510557964274f;     // |log(1e-6)|
  dw = fminf(fmaxf(dw, -MR), MR);
  dh = fminf(fmaxf(dh, -MR), MR);
  float gx = dx * rw + rx;
  float gy = dy * rh + ry;
  float gw = rw * expf(dw);
  float gh = rh * expf(dh);
  float v = da + ANG[a] + 0.7853981633974483f;
  float r = fmodf(v, 3.14159265358979323846f);
  if (r < 0.0f) r += 3.14159265358979323846f;
  float ga = r - 0.7853981633974483f;
  int loc = lvl_off + (hw << 2) + a;
  size_t base = (size_t)b * 436480 + (size_t)loc * 5;
  outb[base + 0] = gx;
  outb[base + 1] = gy;
  outb[base + 2] = gw;
  outb[base + 3] = gh;
  outb[base + 4] = ga;
}

// ============================================================================
extern "C" void kernel_launch(void* const* d_in, const int* in_sizes, int n_in,
                              void* d_out, int out_size, void* d_ws,
                              size_t ws_size, hipStream_t stream) {
  const float* feats[5];
  for (int i = 0; i < 5; ++i) feats[i] = (const float*)d_in[i];
  const float* reg_w0 = (const float*)d_in[5];
  const float* reg_b0 = (const float*)d_in[6];
  const float* reg_w1 = (const float*)d_in[7];
  const float* reg_b1 = (const float*)d_in[8];
  const float* cls_w0 = (const float*)d_in[9];
  const float* cls_b0 = (const float*)d_in[10];
  const float* cls_w1 = (const float*)d_in[11];
  const float* cls_b1 = (const float*)d_in[12];
  const float* reg_head_w = (const float*)d_in[13];
  const float* reg_head_b = (const float*)d_in[14];
  const float* cls_head_w = (const float*)d_in[15];
  const float* cls_head_b = (const float*)d_in[16];
  const float* conf_w = (const float*)d_in[17];
  const float* conf_b = (const float*)d_in[18];

  unsigned short* ws = (unsigned short*)d_ws;
  unsigned short* t1r = ws + 44695552ull;
  unsigned short* t1c = ws + 78249984ull;
  unsigned short* wt4 = ws + 111804416ull;
  unsigned short* wh = ws + 114163712ull;
  unsigned short* wc = ws + 114171904ull;
  unsigned short* zp = ws + 114188288ull;
  float* hbuf_all = (float*)((char*)d_ws + 228376704ull);

  prep_convw<<<9216, 256, 0, stream>>>(reg_w0, reg_w1, cls_w0, cls_w1, wt4);
  prep_small<<<97, 256, 0, stream>>>(cls_head_w, reg_head_w, conf_w, wc, wh,
                                     zp);
  to_nhwc_all<<<2728, 256, 0, stream>>>(feats[0], feats[1], feats[2], feats[3],
                                        feats[4], ws);

  float* scores = (float*)d_out;
  float* boxes = (float*)d_out + SCORES_TOTAL;

  static const int gbase[2] = {0, 131072};
  static const int gM[2] = {131072, 43520};
  for (int g = 0; g < 2; ++g) {
    const int base = gbase[g];
    const int M = gM[g];
    const int nb = M / 256;
    const size_t bofs = ((size_t)base << 8);
    unsigned short* t1r_v = t1r - bofs;  // group-local virtual bases
    unsigned short* t1c_v = t1c - bofs;
    // conv1 both towers in ONE dispatch (grid.y = tower)
    conv256<<<dim3(nb, 2), 512, 0, stream>>>(
        ws, wt4 + 0ull * 589824, wt4 + 2ull * 589824, reg_b0, cls_b0, zp,
        t1r_v, t1c_v, base);
    // conv2 reg tower -> t2 (ws region)
    conv256<<<dim3(nb, 1), 512, 0, stream>>>(
        t1r_v, wt4 + 1ull * 589824, wt4 + 1ull * 589824, reg_b1, reg_b1, zp,
        ws, ws, base);
    head24_mfma<<<nb, 256, 0, stream>>>(ws + bofs, wh, reg_head_b, conf_b,
                                        hbuf_all + (size_t)base * 24);
    // conv2 cls tower -> t2 (ws region, overwrites reg t2 after head24 read)
    conv256<<<dim3(nb, 1), 512, 0, stream>>>(
        t1c_v, wt4 + 3ull * 589824, wt4 + 3ull * 589824, cls_b1, cls_b1, zp,
        ws, ws, base);
    cls_scores<<<nb, 256, 0, stream>>>(ws, wc, cls_head_b, hbuf_all, scores,
                                       base);
  }
  decode_all<<<(174592 * 4 + 255) / 256, 256, 0, stream>>>(hbuf_all, boxes);
}